// Round 12
// baseline (100.067 us; speedup 1.0000x reference)
//
#include <hip/hip_runtime.h>

#define IMG_H 1080
#define IMG_W 1920

// Nonzero iff the 16-bit circular mask has 9 consecutive set bits.
// (Equivalent to reference's 24-bit window test; validated absmax=0 R1-R10.)
__device__ __forceinline__ unsigned det9(unsigned m) {
    unsigned x = m | (m << 16);
    unsigned t = x & (x >> 1);   // run 2
    t &= t >> 2;                 // run 4
    t &= t >> 4;                 // run 8
    t &= x >> 8;                 // run 9
    return t;
}

// m = (m << 1) | (val CMP thr) in exactly 2 VALU (v_cmp + v_addc m+m+carry).
// Validated absmax=0 in R8-R10.
#define STEP_GE(m, sc, val, thr)                                          \
    asm("v_cmp_ge_f32 %1, %2, %3\n\tv_addc_co_u32 %0, %1, %0, %0, %1"     \
        : "+v"(m), "=s"(sc) : "v"(val), "v"(thr))
#define STEP_LE(m, sc, val, thr)                                          \
    asm("v_cmp_le_f32 %1, %2, %3\n\tv_addc_co_u32 %0, %1, %0, %0, %1"     \
        : "+v"(m), "=s"(sc) : "v"(val), "v"(thr))

__global__ __launch_bounds__(256) void fast_score_kernel(const float* __restrict__ img,
                                                         float* __restrict__ out) {
    const int n  = blockIdx.z;
    const int y  = blockIdx.y;                       // one image row per block
    const int gx = blockIdx.x * 256 + threadIdx.x;   // 0..2047 (loads self-clamp)

    const float* base = img + (size_t)n * (IMG_H * IMG_W);

    // 7 replicate-clamped row pointers — block-uniform => SGPR pairs.
    const float* rp0 = base + (size_t)min(max(y - 3, 0), IMG_H - 1) * IMG_W;
    const float* rp1 = base + (size_t)min(max(y - 2, 0), IMG_H - 1) * IMG_W;
    const float* rp2 = base + (size_t)min(max(y - 1, 0), IMG_H - 1) * IMG_W;
    const float* rp3 = base + (size_t)y * IMG_W;
    const float* rp4 = base + (size_t)min(y + 1, IMG_H - 1) * IMG_W;
    const float* rp5 = base + (size_t)min(y + 2, IMG_H - 1) * IMG_W;
    const float* rp6 = base + (size_t)min(y + 3, IMG_H - 1) * IMG_W;

    // 7 replicate-clamped column BYTE offsets (VGPR)
    unsigned off[7];
#pragma unroll
    for (int d = 0; d < 7; ++d) {
        off[d] = (unsigned)min(max(gx + d - 3, 0), IMG_W - 1) * 4u;
    }

    // All 17 tap loads in ONE asm block: 17 outstanding global_load_dword,
    // single vmcnt(0) drain. "=&v" (early-clobber) keeps the async load
    // destinations disjoint from the offset inputs -- a plain "=v" let RA
    // alias them, and in-flight load data clobbered later loads' addresses
    // (R11 crash).
    float center, t0, t1, t2, t3, t4, t5, t6, t7, t8, t9, t10, t11, t12, t13, t14, t15;
    asm volatile(
        "global_load_dword %0,  %20, %27\n\t"   // center (3,3)
        "global_load_dword %1,  %17, %27\n\t"   // k0  (row 3, col 0)
        "global_load_dword %2,  %17, %28\n\t"   // k1  (4,0)
        "global_load_dword %3,  %18, %29\n\t"   // k2  (5,1)
        "global_load_dword %4,  %19, %30\n\t"   // k3  (6,2)
        "global_load_dword %5,  %20, %30\n\t"   // k4  (6,3)
        "global_load_dword %6,  %21, %30\n\t"   // k5  (6,4)
        "global_load_dword %7,  %22, %29\n\t"   // k6  (5,5)
        "global_load_dword %8,  %23, %28\n\t"   // k7  (4,6)
        "global_load_dword %9,  %23, %27\n\t"   // k8  (3,6)
        "global_load_dword %10, %23, %26\n\t"   // k9  (2,6)
        "global_load_dword %11, %22, %25\n\t"   // k10 (1,5)
        "global_load_dword %12, %21, %24\n\t"   // k11 (0,4)
        "global_load_dword %13, %20, %24\n\t"   // k12 (0,3)
        "global_load_dword %14, %19, %24\n\t"   // k13 (0,2)
        "global_load_dword %15, %18, %25\n\t"   // k14 (1,1)
        "global_load_dword %16, %17, %26\n\t"   // k15 (2,0)
        "s_waitcnt vmcnt(0)"
        : "=&v"(center), "=&v"(t0), "=&v"(t1), "=&v"(t2), "=&v"(t3), "=&v"(t4),
          "=&v"(t5), "=&v"(t6), "=&v"(t7), "=&v"(t8), "=&v"(t9), "=&v"(t10),
          "=&v"(t11), "=&v"(t12), "=&v"(t13), "=&v"(t14), "=&v"(t15)
        : "v"(off[0]), "v"(off[1]), "v"(off[2]), "v"(off[3]), "v"(off[4]),
          "v"(off[5]), "v"(off[6]),
          "s"(rp0), "s"(rp1), "s"(rp2), "s"(rp3), "s"(rp4), "s"(rp5), "s"(rp6));

    const float hi = center + 20.0f;
    const float lo = center - 20.0f;
    const float t[16] = {t0, t1, t2, t3, t4, t5, t6, t7,
                         t8, t9, t10, t11, t12, t13, t14, t15};
    unsigned dark = 0u, bright = 0u;
    unsigned long long sc0, sc1;
#pragma unroll
    for (int k = 0; k < 16; ++k) {
        STEP_GE(dark,   sc0, t[k], hi);
        STEP_LE(bright, sc1, t[k], lo);
    }

    const float res = (det9(dark) | det9(bright)) ? 1.0f : 0.0f;
    if (gx < IMG_W) {
        out[(size_t)n * (IMG_H * IMG_W) + (size_t)y * IMG_W + gx] = res;
    }
}

extern "C" void kernel_launch(void* const* d_in, const int* in_sizes, int n_in,
                              void* d_out, int out_size, void* d_ws, size_t ws_size,
                              hipStream_t stream) {
    const float* img = (const float*)d_in[0];
    float* out = (float*)d_out;
    const int n_img = in_sizes[0] / (IMG_H * IMG_W);   // = 4
    dim3 grid((IMG_W + 255) / 256,   // 8
              IMG_H,                 // 1080
              n_img);                // 4  -> 34560 blocks
    fast_score_kernel<<<grid, 256, 0, stream>>>(img, out);
}